// Round 2
// baseline (2332.755 us; speedup 1.0000x reference)
//
#include <hip/hip_runtime.h>

// GCN 3->32->32->1, N=100K, E=6.4M (+self loops).
// R1 counters: k_agg_h 664us, WRITE_SIZE == all atomic dwords -> device-scope
// atomics execute memory-side (~308G dword-atomics/s). This round: halve the
// atomic op count by packing 2 fixed-point f32 features per u64 atomicAdd.
//  - h1 >= 0 (relu), |contrib| << 8, <=~128 in-edges -> lo-half sum < 2^31,
//    no carry into hi half. Scale 2^20 -> quant error ~1e-5 << 4.9e-4 thr.
//  - normv[e] precomputed once (coalesced reuse in all 3 edge kernels).

#define BLK 256
#define FIXS 1048576.0f          // 2^20
#define FIXSI (1.0f / 1048576.0f)

__global__ void k_deg(const int* __restrict__ dst, float* __restrict__ deg, int E) {
    int t = blockIdx.x * blockDim.x + threadIdx.x;
    if (t < E) atomicAdd(&deg[dst[t]], 1.0f);
}

__global__ void k_dis(float* __restrict__ deg, float* __restrict__ dis, int N) {
    int i = blockIdx.x * blockDim.x + threadIdx.x;
    if (i < N) {
        float d = deg[i] + 1.0f;   // + self loop
        deg[i] = d;
        dis[i] = 1.0f / sqrtf(d);
    }
}

// normv[e] = dis[src]*dis[dst]  (dis is 400KB -> L2-resident; coalesced write)
__global__ void k_norm(const int* __restrict__ src, const int* __restrict__ dst,
                       const float* __restrict__ dis, float* __restrict__ normv, int E) {
    int e = blockIdx.x * blockDim.x + threadIdx.x;
    if (e < E) normv[e] = dis[src[e]] * dis[dst[e]];
}

// Layer-1 edge aggregation of raw x (3 feats), 1 thread per edge
__global__ void k_agg_x(const int* __restrict__ src, const int* __restrict__ dst,
                        const float* __restrict__ x, const float* __restrict__ normv,
                        float* __restrict__ aggx, int E) {
    int e = blockIdx.x * blockDim.x + threadIdx.x;
    if (e >= E) return;
    int s = src[e], d = dst[e];
    float nv = normv[e];
#pragma unroll
    for (int f = 0; f < 3; f++)
        atomicAdd(&aggx[d * 4 + f], x[s * 3 + f] * nv);
}

// h1' = relu( (aggx + x*dis^2) @ W1 + b1 ), 32 lanes per node (j = output feat)
__global__ void k_node1(const float* __restrict__ x, const float* __restrict__ aggx,
                        const float* __restrict__ dis,
                        const float* __restrict__ W1, const float* __restrict__ b1,
                        float* __restrict__ h1, int N) {
    int t = blockIdx.x * blockDim.x + threadIdx.x;
    int i = t >> 5;
    int j = t & 31;
    if (i >= N) return;
    float di = dis[i];
    float invd = di * di;          // self-loop norm = dis[i]^2
    float acc = b1[j];
#pragma unroll
    for (int k = 0; k < 3; k++) {
        float a = aggx[i * 4 + k] + x[i * 3 + k] * invd;
        acc += a * W1[k * 32 + j];
    }
    h1[i * 32 + j] = fmaxf(acc, 0.0f);
}

// Layer-2 edge aggregation, 16 lanes/edge, 2 feats packed per u64 atomic.
// h1 >= 0 so both fixed-point halves are non-negative; lo-sum < 2^31 (no carry).
__global__ void k_agg_h16(const int* __restrict__ src, const int* __restrict__ dst,
                          const float* __restrict__ h, const float* __restrict__ normv,
                          unsigned long long* __restrict__ agg, int E) {
    int t = blockIdx.x * blockDim.x + threadIdx.x;
    int e = t >> 4;
    int l = t & 15;
    if (e >= E) return;
    int s = src[e], d = dst[e];
    float nv = normv[e];
    float2 hv = ((const float2*)h)[s * 16 + l];           // 128B coalesced per edge
    unsigned int q0 = (unsigned int)(fminf(hv.x * nv, 8.0f) * FIXS + 0.5f);
    unsigned int q1 = (unsigned int)(fminf(hv.y * nv, 8.0f) * FIXS + 0.5f);
    atomicAdd(&agg[(size_t)d * 16 + l], ((unsigned long long)q1 << 32) | (unsigned long long)q0);
}

// h2' = relu( (agg1 + h1*dis^2) @ W2 + b2 );  p = h2' @ W3  (shuffle-reduced)
__global__ void k_node2(const float* __restrict__ h1, const unsigned int* __restrict__ agg1u,
                        const float* __restrict__ dis,
                        const float* __restrict__ W2, const float* __restrict__ b2,
                        const float* __restrict__ W3,
                        float* __restrict__ p, int N) {
    int t = blockIdx.x * blockDim.x + threadIdx.x;
    int i = t >> 5;
    int j = t & 31;
    if (i >= N) return;
    float di = dis[i];
    float invd = di * di;
    // little-endian u64 halves: u32[i*32 + j] is feature j of node i
    float a = (float)agg1u[i * 32 + j] * FIXSI + h1[i * 32 + j] * invd;
    float acc = b2[j];
#pragma unroll
    for (int k = 0; k < 32; k++) {
        float ak = __shfl(a, k, 32);           // broadcast within 32-lane group
        acc += ak * W2[k * 32 + j];
    }
    float h2 = fmaxf(acc, 0.0f);
    float contrib = h2 * W3[j];
#pragma unroll
    for (int m = 16; m >= 1; m >>= 1)
        contrib += __shfl_xor(contrib, m, 32);
    if (j == 0) p[i] = contrib;
}

// Layer-3 edge aggregation of scalar p, 1 lane per edge
__global__ void k_agg_p(const int* __restrict__ src, const int* __restrict__ dst,
                        const float* __restrict__ p, const float* __restrict__ normv,
                        float* __restrict__ aggp, int E) {
    int e = blockIdx.x * blockDim.x + threadIdx.x;
    if (e >= E) return;
    atomicAdd(&aggp[dst[e]], p[src[e]] * normv[e]);
}

__global__ void k_out(const float* __restrict__ aggp, const float* __restrict__ p,
                      const float* __restrict__ dis, const float* __restrict__ b3,
                      float* __restrict__ out, int N) {
    int i = blockIdx.x * blockDim.x + threadIdx.x;
    if (i < N) {
        float di = dis[i];
        out[i] = aggp[i] + p[i] * di * di + b3[0];
    }
}

extern "C" void kernel_launch(void* const* d_in, const int* in_sizes, int n_in,
                              void* d_out, int out_size, void* d_ws, size_t ws_size,
                              hipStream_t stream) {
    const float* x  = (const float*)d_in[0];
    const int*   ei = (const int*)d_in[1];
    const float* W1 = (const float*)d_in[2];
    const float* b1 = (const float*)d_in[3];
    const float* W2 = (const float*)d_in[4];
    const float* b2 = (const float*)d_in[5];
    const float* W3 = (const float*)d_in[6];
    const float* b3 = (const float*)d_in[7];
    float* out = (float*)d_out;

    int N = in_sizes[0] / 3;
    int E = in_sizes[1] / 2;
    const int* src = ei;
    const int* dst = ei + E;

    // workspace layout (floats). Zeroed region first: deg|aggx|agg64|aggp = 38N f32-equiv
    float* ws   = (float*)d_ws;
    float* deg  = ws;                                   // N
    float* aggx = deg  + N;                             // 4N
    unsigned long long* agg64 = (unsigned long long*)(aggx + 4 * N);  // 16N u64 = 32N f32
    float* aggp = (float*)(agg64 + 16 * (size_t)N);     // N
    float* dis  = aggp + N;                             // N
    float* h1   = dis  + N;                             // 32N
    float* p    = h1   + 32 * N;                        // N
    float* normv = p + N;                               // E

    hipMemsetAsync(ws, 0, (size_t)(38ll * N) * sizeof(float), stream);

    k_deg  <<<(E + BLK - 1) / BLK, BLK, 0, stream>>>(dst, deg, E);
    k_dis  <<<(N + BLK - 1) / BLK, BLK, 0, stream>>>(deg, dis, N);
    k_norm <<<(E + BLK - 1) / BLK, BLK, 0, stream>>>(src, dst, dis, normv, E);

    k_agg_x<<<(E + BLK - 1) / BLK, BLK, 0, stream>>>(src, dst, x, normv, aggx, E);

    long long tn = (long long)N * 32;
    k_node1<<<(unsigned)((tn + BLK - 1) / BLK), BLK, 0, stream>>>(x, aggx, dis, W1, b1, h1, N);

    long long th = (long long)E * 16;
    k_agg_h16<<<(unsigned)((th + BLK - 1) / BLK), BLK, 0, stream>>>(src, dst, h1, normv, agg64, E);

    k_node2<<<(unsigned)((tn + BLK - 1) / BLK), BLK, 0, stream>>>(h1, (const unsigned int*)agg64,
                                                                  dis, W2, b2, W3, p, N);

    k_agg_p<<<(E + BLK - 1) / BLK, BLK, 0, stream>>>(src, dst, p, normv, aggp, E);

    k_out  <<<(N + BLK - 1) / BLK, BLK, 0, stream>>>(aggp, p, dis, b3, out, N);
}

// Round 3
// 1153.958 us; speedup vs baseline: 2.0215x; 2.0215x over previous
//
#include <hip/hip_runtime.h>

// GCN 3->32->32->1, N=100K, E=6.4M (+self loops).
// R2 lesson: device atomics are write-through at the coherent point, costed in
// 32B sectors per wave-instruction; scatter-atomic aggregation floors at ~660us.
// R3: build CSR once (count/scan/scatter), aggregate by GATHER (no atomics in
// the hot kernels). Factor norm = dis[d]*(sum dis[s]*v[s]) -> pre-scaled
// y = dis*x (padded float4), g = dis*h1 (32-wide rows), q = dis*p (scalar).

#define BLK 256

// ---- CSR build ----------------------------------------------------------

__global__ void k_count(const int* __restrict__ dst, int* __restrict__ count, int E) {
    int t = blockIdx.x * blockDim.x + threadIdx.x;
    if (t < E) atomicAdd(&count[dst[t]], 1);
}

// per-block exclusive scan, block sums out
__global__ void k_scan1(const int* __restrict__ count, int* __restrict__ excl,
                        int* __restrict__ bsum, int N) {
    __shared__ int sh[BLK];
    int i = blockIdx.x * BLK + threadIdx.x;
    int v = (i < N) ? count[i] : 0;
    sh[threadIdx.x] = v;
    __syncthreads();
    for (int off = 1; off < BLK; off <<= 1) {
        int t = (threadIdx.x >= off) ? sh[threadIdx.x - off] : 0;
        __syncthreads();
        sh[threadIdx.x] += t;
        __syncthreads();
    }
    if (i < N) excl[i] = sh[threadIdx.x] - v;          // exclusive within block
    if (threadIdx.x == BLK - 1) bsum[blockIdx.x] = sh[threadIdx.x];
}

// single-block scan of block sums (nb <= 512)
__global__ void k_scan2(int* __restrict__ bsum, int nb) {
    __shared__ int sh[512];
    int v = (threadIdx.x < nb) ? bsum[threadIdx.x] : 0;
    sh[threadIdx.x] = v;
    __syncthreads();
    for (int off = 1; off < 512; off <<= 1) {
        int t = (threadIdx.x >= off) ? sh[threadIdx.x - off] : 0;
        __syncthreads();
        sh[threadIdx.x] += t;
        __syncthreads();
    }
    if (threadIdx.x < nb) bsum[threadIdx.x] = sh[threadIdx.x] - v;  // exclusive
}

// rowptr/cursor/dis/y4 from count + scan results
__global__ void k_finish(const int* __restrict__ count, const int* __restrict__ excl,
                         const int* __restrict__ bsum,
                         int* __restrict__ rowptr, int* __restrict__ cursor,
                         float* __restrict__ dis, const float* __restrict__ x,
                         float4* __restrict__ y4, int N, int E) {
    int i = blockIdx.x * blockDim.x + threadIdx.x;
    if (i < N) {
        int r = excl[i] + bsum[i / BLK];
        rowptr[i] = r;
        cursor[i] = r;
        float di = rsqrtf((float)count[i] + 1.0f);   // + self loop
        dis[i] = di;
        float4 y;
        y.x = di * x[3 * i + 0];
        y.y = di * x[3 * i + 1];
        y.z = di * x[3 * i + 2];
        y.w = 0.0f;
        y4[i] = y;
    }
    if (i == 0) rowptr[N] = E;
}

__global__ void k_scatter(const int* __restrict__ src, const int* __restrict__ dst,
                          int* __restrict__ cursor, int* __restrict__ csr, int E) {
    int e = blockIdx.x * blockDim.x + threadIdx.x;
    if (e >= E) return;
    int pos = atomicAdd(&cursor[dst[e]], 1);
    csr[pos] = src[e];
}

// ---- fused layers (gather, no atomics) ----------------------------------

// Layer 1: 32 lanes/node. Lanes stride the edge list gathering y4 (16B each),
// butterfly-reduce, then lane j computes h1_j and stores g = dis*h1.
__global__ void k_l1(const int* __restrict__ csr, const int* __restrict__ rowptr,
                     const float4* __restrict__ y4, const float* __restrict__ dis,
                     const float* __restrict__ W1, const float* __restrict__ b1,
                     float* __restrict__ g, int N) {
    int t = blockIdx.x * blockDim.x + threadIdx.x;
    int i = t >> 5, j = t & 31;
    if (i >= N) return;
    int beg = rowptr[i], end = rowptr[i + 1];
    float ax = 0.f, ay = 0.f, az = 0.f;
    for (int e = beg + j; e < end; e += 32) {
        float4 yv = y4[csr[e]];
        ax += yv.x; ay += yv.y; az += yv.z;
    }
#pragma unroll
    for (int m = 16; m >= 1; m >>= 1) {
        ax += __shfl_xor(ax, m, 32);
        ay += __shfl_xor(ay, m, 32);
        az += __shfl_xor(az, m, 32);
    }
    float di = dis[i];
    float4 ys = y4[i];                      // self loop (y already dis-scaled)
    float a0 = di * (ax + ys.x);
    float a1 = di * (ay + ys.y);
    float a2 = di * (az + ys.z);
    float h = b1[j] + a0 * W1[0 * 32 + j] + a1 * W1[1 * 32 + j] + a2 * W1[2 * 32 + j];
    h = fmaxf(h, 0.0f);
    g[i * 32 + j] = di * h;
}

// Layer 2 + 3 projection: 32 lanes/node, lane j = feature j.
// Coalesced csr chunk load, shuffle-broadcast edge ids, 128B row gathers.
__global__ void k_l2(const int* __restrict__ csr, const int* __restrict__ rowptr,
                     const float* __restrict__ g, const float* __restrict__ dis,
                     const float* __restrict__ W2, const float* __restrict__ b2,
                     const float* __restrict__ W3,
                     float* __restrict__ q, int N) {
    int t = blockIdx.x * blockDim.x + threadIdx.x;
    int i = t >> 5, j = t & 31;
    if (i >= N) return;
    int beg = rowptr[i], end = rowptr[i + 1];
    float acc = 0.f;
    for (int k0 = beg; k0 < end; k0 += 32) {
        int e = k0 + j;
        int myedge = (e < end) ? csr[e] : 0;      // coalesced
        int cnt = min(32, end - k0);
        for (int t2 = 0; t2 < cnt; t2++) {
            int s = __shfl(myedge, t2, 32);       // broadcast edge id
            acc += g[s * 32 + j];                 // 128B coalesced row
        }
    }
    float di = dis[i];
    float a = di * (acc + g[i * 32 + j]);         // + self loop
    float o = b2[j];
#pragma unroll
    for (int k = 0; k < 32; k++)
        o += __shfl(a, k, 32) * W2[k * 32 + j];
    float h2 = fmaxf(o, 0.0f);
    float contrib = h2 * W3[j];
#pragma unroll
    for (int m = 16; m >= 1; m >>= 1)
        contrib += __shfl_xor(contrib, m, 32);
    if (j == 0) q[i] = di * contrib;              // q = dis * p
}

// Layer 3: 32 lanes/node, scalar q gathers, butterfly reduce.
__global__ void k_l3(const int* __restrict__ csr, const int* __restrict__ rowptr,
                     const float* __restrict__ q, const float* __restrict__ dis,
                     const float* __restrict__ b3, float* __restrict__ out, int N) {
    int t = blockIdx.x * blockDim.x + threadIdx.x;
    int i = t >> 5, j = t & 31;
    if (i >= N) return;
    int beg = rowptr[i], end = rowptr[i + 1];
    float acc = 0.f;
    for (int e = beg + j; e < end; e += 32)
        acc += q[csr[e]];
#pragma unroll
    for (int m = 16; m >= 1; m >>= 1)
        acc += __shfl_xor(acc, m, 32);
    if (j == 0) out[i] = dis[i] * (acc + q[i]) + b3[0];
}

extern "C" void kernel_launch(void* const* d_in, const int* in_sizes, int n_in,
                              void* d_out, int out_size, void* d_ws, size_t ws_size,
                              hipStream_t stream) {
    const float* x  = (const float*)d_in[0];
    const int*   ei = (const int*)d_in[1];
    const float* W1 = (const float*)d_in[2];
    const float* b1 = (const float*)d_in[3];
    const float* W2 = (const float*)d_in[4];
    const float* b2 = (const float*)d_in[5];
    const float* W3 = (const float*)d_in[6];
    const float* b3 = (const float*)d_in[7];
    float* out = (float*)d_out;

    int N = in_sizes[0] / 3;
    int E = in_sizes[1] / 2;
    const int* src = ei;
    const int* dst = ei + E;
    int nb = (N + BLK - 1) / BLK;             // scan blocks (391 <= 512)

    // workspace layout (4-byte words)
    char* w = (char*)d_ws;
    int*   count  = (int*)w;                 w += (size_t)N * 4;
    int*   excl   = (int*)w;                 w += (size_t)N * 4;
    int*   bsum   = (int*)w;                 w += 1024 * 4;
    int*   rowptr = (int*)w;                 w += (size_t)(N + 1) * 4;
    int*   cursor = (int*)w;                 w += (size_t)N * 4;
    float* dis    = (float*)w;               w += (size_t)N * 4;
    float* y4     = (float*)w;               w += (size_t)N * 16;     // float4[N]
    float* g      = (float*)w;               w += (size_t)N * 32 * 4; // [N][32]
    float* q      = (float*)w;               w += (size_t)N * 4;
    int*   csr    = (int*)w;                 w += (size_t)E * 4;

    hipMemsetAsync(count, 0, (size_t)N * 4, stream);

    k_count  <<<(E + BLK - 1) / BLK, BLK, 0, stream>>>(dst, count, E);
    k_scan1  <<<nb, BLK, 0, stream>>>(count, excl, bsum, N);
    k_scan2  <<<1, 512, 0, stream>>>(bsum, nb);
    k_finish <<<nb, BLK, 0, stream>>>(count, excl, bsum, rowptr, cursor,
                                      dis, x, (float4*)y4, N, E);
    k_scatter<<<(E + BLK - 1) / BLK, BLK, 0, stream>>>(src, dst, cursor, csr, E);

    long long tn = (long long)N * 32;
    unsigned gn = (unsigned)((tn + BLK - 1) / BLK);
    k_l1<<<gn, BLK, 0, stream>>>(csr, rowptr, (const float4*)y4, dis, W1, b1, g, N);
    k_l2<<<gn, BLK, 0, stream>>>(csr, rowptr, g, dis, W2, b2, W3, q, N);
    k_l3<<<gn, BLK, 0, stream>>>(csr, rowptr, q, dis, b3, out, N);
}